// Round 16
// baseline (667.251 us; speedup 1.0000x reference)
//
#include <hip/hip_runtime.h>
#include <hip/hip_cooperative_groups.h>
#include <math.h>

namespace cg = cooperative_groups;

#define NN 262144
#define DD 128
#define EPS_SL 1e-8f
#define EPS_LN 1e-5f
#define THREADS 512
#define TILE_M 64
#define NBLOCKS 256
#define NTILES (NN / TILE_M)          // 4096
#define TPB (NTILES / NBLOCKS)        // 16

typedef __attribute__((ext_vector_type(8))) short bf16x8;
typedef __attribute__((ext_vector_type(4))) float f32x4;

// LDS layout (bytes). Subtiled MFMA-native [kb][row][8] bf16; X XOR-swizzled.
#define OFF_W1 0                       // [36][128][8] bf16 = 73728 B  (K=288 pad)
#define OFF_W2 73728                   // [16][128][8] bf16 = 32768 B
#define OFF_X  106496                  // [36][64][8]  bf16 = 36864 B
#define OFF_H  143360                  // [16][64][8]  bf16 = 16384 B
#define OFF_RED 159744                 // 256 float2   =  2048 B
#define SMEM_TOT 161792

// d_ws layout (CSR build)
#define WS_OFFS   0                    // (NN+1) int
#define WS_CURSOR 1048832              // NN int
#define WS_BSUM   2097408              // 1024 int
#define WS_ESRC   2101504              // E int

__device__ inline unsigned short f2bf(float f) {
    union { float f; unsigned int i; } v; v.f = f;
    unsigned int r = v.i + 0x7fffu + ((v.i >> 16) & 1u);
    return (unsigned short)(r >> 16);
}
__device__ inline unsigned int pack2(float a, float b) {
    return (unsigned int)f2bf(a) | ((unsigned int)f2bf(b) << 16);
}
__device__ inline uint4 pack8(float4 a, float4 b) {
    return make_uint4(pack2(a.x, a.y), pack2(a.z, a.w),
                      pack2(b.x, b.y), pack2(b.z, b.w));
}
__device__ inline float signed_log(float x) {
    float l = __logf(fabsf(x) + EPS_SL);
    return (x > 0.f) ? l : ((x < 0.f) ? -l : 0.f);
}
// swizzled X store/load: unit index (kb*64+row) ^ (kb&7)
__device__ inline void stx(unsigned short* sX, int kb, int row, uint4 v) {
    *(uint4*)(sX + (((kb * 64 + row) ^ (kb & 7)) * 8)) = v;
}
__device__ inline bf16x8 ldx(const unsigned short* sX, int kb, int row) {
    return *(const bf16x8*)(sX + (((kb * 64 + row) ^ (kb & 7)) * 8));
}

// LDS-only block barrier (no vmcnt drain; r10-proven)
__device__ inline void block_sync_lds() {
    __builtin_amdgcn_sched_barrier(0);
    asm volatile("s_waitcnt lgkmcnt(0)" ::: "memory");
    __builtin_amdgcn_s_barrier();
    __builtin_amdgcn_sched_barrier(0);
}

// ============ cooperative single-kernel CSR build ============
// grid MUST be 1024 x 256 (gtid covers NN exactly; 4 blocks/CU co-resident).
__global__ void csr_build(const int* __restrict__ src, const int* __restrict__ dst,
                          int* offs, int* cursor, int* bsum, int* esrc, int E) {
    cg::grid_group grid = cg::this_grid();
    __shared__ int tmp[256];
    __shared__ int wsum[4];
    const int t = threadIdx.x, b = blockIdx.x;
    const int gtid = b * 256 + t;          // 0..NN-1

    // P0: zero counts
    offs[gtid] = 0;
    grid.sync();

    // P1: histogram (2 edges/thread, grid-stride for safety)
    for (int e = gtid * 2; e < E; e += NN * 2) {
        if (e + 1 < E) {
            int2 d = *(const int2*)(dst + e);
            atomicAdd(&offs[d.x], 1);
            atomicAdd(&offs[d.y], 1);
        } else {
            atomicAdd(&offs[dst[e]], 1);
        }
    }
    grid.sync();

    // P2: block-local exclusive scan over this block's 256 counts
    int own = offs[gtid];
    tmp[t] = own;
    __syncthreads();
    for (int off = 1; off < 256; off <<= 1) {
        int v = (t >= off) ? tmp[t - off] : 0;
        __syncthreads();
        tmp[t] += v;
        __syncthreads();
    }
    int excl = tmp[t] - own;
    if (t == 255) bsum[b] = tmp[255];
    grid.sync();

    // P3: per-block prefix over bsum[0..b) + apply
    int acc = 0;
    #pragma unroll
    for (int j = 0; j < 4; ++j) {
        int idx = j * 256 + t;
        acc += (idx < b) ? bsum[idx] : 0;
    }
    #pragma unroll
    for (int off = 1; off < 64; off <<= 1) acc += __shfl_xor(acc, off);
    if ((t & 63) == 0) wsum[t >> 6] = acc;
    __syncthreads();
    int prefix = wsum[0] + wsum[1] + wsum[2] + wsum[3];
    int v = excl + prefix;
    offs[gtid] = v;
    cursor[gtid] = v;
    if (gtid == 0) offs[NN] = E;
    grid.sync();

    // P4: fill edge lists
    for (int e = gtid * 2; e < E; e += NN * 2) {
        if (e + 1 < E) {
            int2 s = *(const int2*)(src + e);
            int2 d = *(const int2*)(dst + e);
            int p0 = atomicAdd(&cursor[d.x], 1);
            esrc[p0] = s.x;
            int p1 = atomicAdd(&cursor[d.y], 1);
            esrc[p1] = s.y;
        } else {
            int p = atomicAdd(&cursor[dst[e]], 1);
            esrc[p] = src[e];
        }
    }
}

// ---------------- non-cooperative CSR fallback (r15-proven) ----------------
__global__ void hist_kernel(const int* __restrict__ dst, int* counts, int E) {
    int t = blockIdx.x * blockDim.x + threadIdx.x;
    int e = t * 2;
    if (e + 1 < E) {
        int2 d = *(const int2*)(dst + e);
        atomicAdd(&counts[d.x], 1);
        atomicAdd(&counts[d.y], 1);
    } else if (e < E) {
        atomicAdd(&counts[dst[e]], 1);
    }
}

__global__ void scan_local(int* offs, int* bsum) {
    __shared__ int tmp[256];
    int t = threadIdx.x, i = blockIdx.x * 256 + t;
    int own = offs[i];
    tmp[t] = own;
    __syncthreads();
    for (int off = 1; off < 256; off <<= 1) {
        int v = (t >= off) ? tmp[t - off] : 0;
        __syncthreads();
        tmp[t] += v;
        __syncthreads();
    }
    offs[i] = tmp[t] - own;
    if (t == 255) bsum[blockIdx.x] = tmp[255];
}

__global__ void scan_fixup(int* offs, const int* __restrict__ bsum, int* cursor, int E) {
    __shared__ int wsum[4];
    const int b = blockIdx.x;
    const int t = threadIdx.x;
    int acc = 0;
    #pragma unroll
    for (int j = 0; j < 4; ++j) {
        int idx = j * 256 + t;
        acc += (idx < b) ? bsum[idx] : 0;
    }
    #pragma unroll
    for (int off = 1; off < 64; off <<= 1) acc += __shfl_xor(acc, off);
    if ((t & 63) == 0) wsum[t >> 6] = acc;
    __syncthreads();
    int prefix = wsum[0] + wsum[1] + wsum[2] + wsum[3];
    int i = b * 256 + t;
    int v = offs[i] + prefix;
    offs[i] = v;
    cursor[i] = v;
    if (i == 0) offs[NN] = E;
}

__global__ void fill_kernel(const int* __restrict__ src, const int* __restrict__ dst,
                            int* cursor, int* esrc, int E) {
    int t = blockIdx.x * blockDim.x + threadIdx.x;
    int e = t * 2;
    if (e + 1 < E) {
        int2 s = *(const int2*)(src + e);
        int2 d = *(const int2*)(dst + e);
        int p0 = atomicAdd(&cursor[d.x], 1);
        esrc[p0] = s.x;
        int p1 = atomicAdd(&cursor[d.y], 1);
        esrc[p1] = s.y;
    } else if (e < E) {
        int p = atomicAdd(&cursor[dst[e]], 1);
        esrc[p] = src[e];
    }
}

// ---------------- CSR gather -> upstream bf16 (one row per 512B out slot) ----
__global__ __launch_bounds__(256) void gather_kernel(
    const float4* __restrict__ h4, const int* __restrict__ offs,
    const int* __restrict__ esrc, char* outb)
{
    int stride = gridDim.x * 256;
    for (int idx = blockIdx.x * 256 + threadIdx.x; idx < NN * 16; idx += stride) {
        int n = idx >> 4, c = idx & 15;
        int o0 = offs[n], o1 = offs[n + 1];
        float4 a = make_float4(0.f, 0.f, 0.f, 0.f);
        float4 b = make_float4(0.f, 0.f, 0.f, 0.f);
        for (int e = o0; e < o1; ++e) {
            const float4* hr = h4 + (size_t)esrc[e] * 32 + c * 2;
            float4 p0 = hr[0], p1 = hr[1];
            a.x += p0.x; a.y += p0.y; a.z += p0.z; a.w += p0.w;
            b.x += p1.x; b.y += p1.y; b.z += p1.z; b.w += p1.w;
        }
        *(uint4*)(outb + (size_t)n * 512 + c * 16) = pack8(a, b);
    }
}

// ---------------- fallback atomic scatter ----------------
__global__ void scatter_kernel(const float4* __restrict__ h4,
                               const int* __restrict__ src,
                               const int* __restrict__ dst,
                               float* up, int E) {
    int tid = blockIdx.x * blockDim.x + threadIdx.x;
    int e = tid >> 5;
    if (e >= E) return;
    int c = tid & 31;
    float4 v = h4[(size_t)src[e] * 32 + c];
    float* o = up + (size_t)dst[e] * DD + c * 4;
    atomicAdd(o + 0, v.x);
    atomicAdd(o + 1, v.y);
    atomicAdd(o + 2, v.z);
    atomicAdd(o + 3, v.w);
}

// ---------------- pipelined MFMA node MLP + LayerNorm (champion) ----------
template <int GATHER>
__global__ __launch_bounds__(THREADS) void node_kernel(
    const float* __restrict__ h, const void* up,
    const float* __restrict__ c1, const float* __restrict__ c2,
    const float* __restrict__ c3, const float* __restrict__ c4,
    const float* __restrict__ qn,
    const float* __restrict__ W1, const float* __restrict__ b1,
    const float* __restrict__ W2, const float* __restrict__ b2,
    const float* __restrict__ gamma, const float* __restrict__ beta,
    float* out)
{
    extern __shared__ char smem[];
    unsigned short* sW1 = (unsigned short*)(smem + OFF_W1);
    unsigned short* sW2 = (unsigned short*)(smem + OFF_W2);
    unsigned short* sX  = (unsigned short*)(smem + OFF_X);
    unsigned short* sH  = (unsigned short*)(smem + OFF_H);
    float2* red = (float2*)(smem + OFF_RED);

    const int tid = threadIdx.x;

    for (int c = tid; c < 36 * 128; c += THREADS) {
        int kb = c >> 7, n = c & 127;
        unsigned short tmp[8] __attribute__((aligned(16)));
        #pragma unroll
        for (int j = 0; j < 8; ++j) {
            int k = kb * 8 + j;
            tmp[j] = (k < 261) ? f2bf(W1[k * DD + n]) : (unsigned short)0;
        }
        *(uint4*)(sW1 + c * 8) = *(const uint4*)tmp;
    }
    for (int c = tid; c < 16 * 128; c += THREADS) {
        int kb = c >> 7, n = c & 127;
        unsigned short tmp[8] __attribute__((aligned(16)));
        #pragma unroll
        for (int j = 0; j < 8; ++j) tmp[j] = f2bf(W2[(kb * 8 + j) * DD + n]);
        *(uint4*)(sW2 + c * 8) = *(const uint4*)tmp;
    }
    if (tid < 192) {
        int kb = 33 + (tid >> 6), row = tid & 63;
        stx(sX, kb, row, make_uint4(0u, 0u, 0u, 0u));
    }

    const int lane = tid & 63;
    const int w    = tid >> 6;
    const int wm   = w >> 2;
    const int wn   = w & 3;
    const int l15  = lane & 15;
    const int lk   = lane >> 4;
    const int col0 = wn * 32 + l15;
    const int col1 = col0 + 16;

    const float b1v[2] = {b1[col0], b1[col1]};
    const float b2v[2] = {b2[col0], b2[col1]};
    const float gv[2]  = {gamma[col0], gamma[col1]};
    const float bv[2]  = {beta[col0], beta[col1]};

    const bf16x8* W1f = (const bf16x8*)sW1;
    const bf16x8* Hf  = (const bf16x8*)sH;
    const bf16x8* W2f = (const bf16x8*)sW2;

    const int k0 = tid & 15;
    const int r0 = tid >> 4;          // 0..31

    float4 h0a, h0b, h1a, h1b;
    uint4  u0, u1;
    float4 v0a, v0b, v1a, v1b;
    float pc1 = 0.f, pc2 = 0.f, pc3 = 0.f, pc4 = 0.f, pc5 = 0.f;

    {
        int base = blockIdx.x * TPB * TILE_M;
        const float* hp = h + (size_t)(base + r0) * DD + k0 * 8;
        h0a = *(const float4*)hp;       h0b = *(const float4*)(hp + 4);
        h1a = *(const float4*)(hp + 32 * DD); h1b = *(const float4*)(hp + 32 * DD + 4);
        if (GATHER) {
            const char* ub = (const char*)up;
            u0 = *(const uint4*)(ub + (size_t)(base + r0) * 512 + k0 * 16);
            u1 = *(const uint4*)(ub + (size_t)(base + r0 + 32) * 512 + k0 * 16);
        } else {
            const float* uf = (const float*)up + (size_t)(base + r0) * DD + k0 * 8;
            v0a = *(const float4*)uf;       v0b = *(const float4*)(uf + 4);
            v1a = *(const float4*)(uf + 32 * DD); v1b = *(const float4*)(uf + 32 * DD + 4);
        }
        if (tid < 64) {
            int n0 = base + tid;
            pc1 = c1[n0]; pc2 = c2[n0]; pc3 = c3[n0]; pc4 = c4[n0]; pc5 = qn[n0];
        }
    }
    __syncthreads();

    for (int tt = 0; tt < TPB; ++tt) {
        const int base = (blockIdx.x * TPB + tt) * TILE_M;

        stx(sX, k0, r0,      pack8(h0a, h0b));
        stx(sX, k0, r0 + 32, pack8(h1a, h1b));
        if (GATHER) {
            stx(sX, 16 + k0, r0,      u0);
            stx(sX, 16 + k0, r0 + 32, u1);
        } else {
            stx(sX, 16 + k0, r0,      pack8(v0a, v0b));
            stx(sX, 16 + k0, r0 + 32, pack8(v1a, v1b));
        }
        if (tid < 64) {
            uint4 pv = make_uint4(pack2(signed_log(pc1), signed_log(pc2)),
                                  pack2(signed_log(pc3), signed_log(pc4)),
                                  pack2(signed_log(pc5), 0.f), 0u);
            stx(sX, 32, tid, pv);
        }

        if (tt + 1 < TPB) {
            int bn = base + TILE_M;
            const float* hp = h + (size_t)(bn + r0) * DD + k0 * 8;
            h0a = *(const float4*)hp;       h0b = *(const float4*)(hp + 4);
            h1a = *(const float4*)(hp + 32 * DD); h1b = *(const float4*)(hp + 32 * DD + 4);
            if (GATHER) {
                const char* ub = (const char*)up;
                u0 = *(const uint4*)(ub + (size_t)(bn + r0) * 512 + k0 * 16);
                u1 = *(const uint4*)(ub + (size_t)(bn + r0 + 32) * 512 + k0 * 16);
            } else {
                const float* uf = (const float*)up + (size_t)(bn + r0) * DD + k0 * 8;
                v0a = *(const float4*)uf;       v0b = *(const float4*)(uf + 4);
                v1a = *(const float4*)(uf + 32 * DD); v1b = *(const float4*)(uf + 32 * DD + 4);
            }
            if (tid < 64) {
                int n0 = bn + tid;
                pc1 = c1[n0]; pc2 = c2[n0]; pc3 = c3[n0]; pc4 = c4[n0]; pc5 = qn[n0];
            }
        }
        block_sync_lds();   // B1: sX ready

        f32x4 acc[2][2] = {};
        #pragma unroll
        for (int ks = 0; ks < 9; ++ks) {
            int kb = ks * 4 + lk;
            bf16x8 a0  = ldx(sX, kb, wm * 32 + l15);
            bf16x8 a1  = ldx(sX, kb, wm * 32 + 16 + l15);
            bf16x8 bb0 = W1f[kb * 128 + col0];
            bf16x8 bb1 = W1f[kb * 128 + col1];
            acc[0][0] = __builtin_amdgcn_mfma_f32_16x16x32_bf16(a0, bb0, acc[0][0], 0, 0, 0);
            acc[0][1] = __builtin_amdgcn_mfma_f32_16x16x32_bf16(a0, bb1, acc[0][1], 0, 0, 0);
            acc[1][0] = __builtin_amdgcn_mfma_f32_16x16x32_bf16(a1, bb0, acc[1][0], 0, 0, 0);
            acc[1][1] = __builtin_amdgcn_mfma_f32_16x16x32_bf16(a1, bb1, acc[1][1], 0, 0, 0);
        }
        #pragma unroll
        for (int fm = 0; fm < 2; ++fm) {
            int row = wm * 32 + fm * 16 + lk * 4;
            #pragma unroll
            for (int fn = 0; fn < 2; ++fn) {
                int col = wn * 32 + fn * 16 + l15;
                int kbh = col >> 3, ko = col & 7;
                #pragma unroll
                for (int r = 0; r < 4; ++r) {
                    float v = acc[fm][fn][r] + b1v[fn];
                    float sg = 1.f / (1.f + __expf(-v));
                    sH[(kbh * 64 + row + r) * 8 + ko] = f2bf(v * sg);
                }
            }
        }
        block_sync_lds();   // B2: sH ready

        f32x4 acc2[2][2] = {};
        #pragma unroll
        for (int ks = 0; ks < 4; ++ks) {
            int kb = ks * 4 + lk;
            bf16x8 a0  = Hf[kb * 64 + wm * 32 + l15];
            bf16x8 a1  = Hf[kb * 64 + wm * 32 + 16 + l15];
            bf16x8 bb0 = W2f[kb * 128 + col0];
            bf16x8 bb1 = W2f[kb * 128 + col1];
            acc2[0][0] = __builtin_amdgcn_mfma_f32_16x16x32_bf16(a0, bb0, acc2[0][0], 0, 0, 0);
            acc2[0][1] = __builtin_amdgcn_mfma_f32_16x16x32_bf16(a0, bb1, acc2[0][1], 0, 0, 0);
            acc2[1][0] = __builtin_amdgcn_mfma_f32_16x16x32_bf16(a1, bb0, acc2[1][0], 0, 0, 0);
            acc2[1][1] = __builtin_amdgcn_mfma_f32_16x16x32_bf16(a1, bb1, acc2[1][1], 0, 0, 0);
        }

        float rs1[2][4], rs2[2][4];
        #pragma unroll
        for (int fm = 0; fm < 2; ++fm) {
            #pragma unroll
            for (int r = 0; r < 4; ++r) {
                size_t rowg = (size_t)(base + wm * 32 + fm * 16 + lk * 4 + r) * DD;
                float z0 = acc2[fm][0][r] + b2v[0] + h[rowg + col0];
                float z1 = acc2[fm][1][r] + b2v[1] + h[rowg + col1];
                acc2[fm][0][r] = z0; acc2[fm][1][r] = z1;
                float s = z0 + z1, q = z0 * z0 + z1 * z1;
                #pragma unroll
                for (int off = 1; off < 16; off <<= 1) {
                    s += __shfl_xor(s, off);
                    q += __shfl_xor(q, off);
                }
                rs1[fm][r] = s; rs2[fm][r] = q;
            }
        }
        if (l15 == 0) {
            #pragma unroll
            for (int fm = 0; fm < 2; ++fm)
                #pragma unroll
                for (int r = 0; r < 4; ++r)
                    red[wn * 64 + wm * 32 + fm * 16 + lk * 4 + r] =
                        make_float2(rs1[fm][r], rs2[fm][r]);
        }
        block_sync_lds();   // B3: red ready

        #pragma unroll
        for (int fm = 0; fm < 2; ++fm) {
            #pragma unroll
            for (int r = 0; r < 4; ++r) {
                int rloc = wm * 32 + fm * 16 + lk * 4 + r;
                float2 t0 = red[rloc], t1 = red[64 + rloc],
                       t2 = red[128 + rloc], t3 = red[192 + rloc];
                float S = t0.x + t1.x + t2.x + t3.x;
                float Q = t0.y + t1.y + t2.y + t3.y;
                float mean = S * (1.f / 128.f);
                float var  = Q * (1.f / 128.f) - mean * mean;
                float rstd = rsqrtf(var + EPS_LN);
                size_t rowg = (size_t)(base + rloc) * DD;
                out[rowg + col0] = (acc2[fm][0][r] - mean) * rstd * gv[0] + bv[0];
                out[rowg + col1] = (acc2[fm][1][r] - mean) * rstd * gv[1] + bv[1];
            }
        }
    }
}

extern "C" void kernel_launch(void* const* d_in, const int* in_sizes, int n_in,
                              void* d_out, int out_size, void* d_ws, size_t ws_size,
                              hipStream_t stream) {
    const float* h     = (const float*)d_in[0];
    const float* c1    = (const float*)d_in[1];
    const float* c2    = (const float*)d_in[2];
    const float* c3    = (const float*)d_in[3];
    const float* c4    = (const float*)d_in[4];
    const float* qn    = (const float*)d_in[5];
    const int*   src   = (const int*)d_in[6];
    const int*   dst   = (const int*)d_in[7];
    const float* W1    = (const float*)d_in[8];
    const float* b1    = (const float*)d_in[9];
    const float* W2    = (const float*)d_in[10];
    const float* b2    = (const float*)d_in[11];
    const float* gamma = (const float*)d_in[12];
    const float* beta  = (const float*)d_in[13];
    float* out = (float*)d_out;
    int E = in_sizes[6];
    size_t ws_needed = (size_t)WS_ESRC + (size_t)E * 4;

    if (ws_size >= ws_needed) {
        char* ws = (char*)d_ws;
        int* offs   = (int*)(ws + WS_OFFS);
        int* cursor = (int*)(ws + WS_CURSOR);
        int* bsum   = (int*)(ws + WS_BSUM);
        int* esrc   = (int*)(ws + WS_ESRC);

        // single cooperative CSR build (zero+hist+scan+fixup+fill)
        void* args[7] = {(void*)&src, (void*)&dst, (void*)&offs, (void*)&cursor,
                         (void*)&bsum, (void*)&esrc, (void*)&E};
        hipError_t ce = hipLaunchCooperativeKernel(
            reinterpret_cast<const void*>(&csr_build),
            dim3(1024), dim3(256), args, 0, stream);
        if (ce != hipSuccess) {
            // fallback: proven non-cooperative chain
            hipMemsetAsync(offs, 0, (size_t)NN * sizeof(int), stream);
            int eb2 = (E / 2 + 255) / 256;
            hist_kernel<<<eb2, 256, 0, stream>>>(dst, offs, E);
            scan_local<<<NN / 256, 256, 0, stream>>>(offs, bsum);
            scan_fixup<<<NN / 256, 256, 0, stream>>>(offs, bsum, cursor, E);
            fill_kernel<<<eb2, 256, 0, stream>>>(src, dst, cursor, esrc, E);
        }

        gather_kernel<<<2048, 256, 0, stream>>>((const float4*)h, offs, esrc, (char*)d_out);

        hipFuncSetAttribute(reinterpret_cast<const void*>(&node_kernel<1>),
                            hipFuncAttributeMaxDynamicSharedMemorySize, SMEM_TOT);
        node_kernel<1><<<NBLOCKS, THREADS, SMEM_TOT, stream>>>(
            h, d_out, c1, c2, c3, c4, qn,
            W1, b1, W2, b2, gamma, beta, out);
    } else {
        // fallback: atomic scatter into d_out (fp32 upstream)
        hipMemsetAsync(d_out, 0, (size_t)NN * DD * sizeof(float), stream);
        int sthreads = E * 32;
        int sblocks = (sthreads + 255) / 256;
        scatter_kernel<<<sblocks, 256, 0, stream>>>((const float4*)h, src, dst, out, E);
        hipFuncSetAttribute(reinterpret_cast<const void*>(&node_kernel<0>),
                            hipFuncAttributeMaxDynamicSharedMemorySize, SMEM_TOT);
        node_kernel<0><<<NBLOCKS, THREADS, SMEM_TOT, stream>>>(
            h, d_out, c1, c2, c3, c4, qn,
            W1, b1, W2, b2, gamma, beta, out);
    }
}

// Round 17
// 226.603 us; speedup vs baseline: 2.9446x; 2.9446x over previous
//
#include <hip/hip_runtime.h>
#include <math.h>

#define NN 262144
#define DD 128
#define EPS_SL 1e-8f
#define EPS_LN 1e-5f
#define THREADS 512
#define TILE_M 64
#define NBLOCKS 256
#define NTILES (NN / TILE_M)          // 4096
#define TPB (NTILES / NBLOCKS)        // 16

typedef __attribute__((ext_vector_type(8))) short bf16x8;
typedef __attribute__((ext_vector_type(4))) float f32x4;

// LDS layout (bytes). Subtiled MFMA-native [kb][row][8] bf16; X XOR-swizzled.
#define OFF_W1 0                       // [36][128][8] bf16 = 73728 B  (K=288 pad)
#define OFF_W2 73728                   // [16][128][8] bf16 = 32768 B
#define OFF_X  106496                  // [36][64][8]  bf16 = 36864 B
#define OFF_H  143360                  // [16][64][8]  bf16 = 16384 B
#define OFF_RED 159744                 // 256 float2   =  2048 B
#define SMEM_TOT 161792

// d_ws layout (CSR build)
#define WS_OFFS   0                    // (NN+1) int
#define WS_CURSOR 1048832              // NN int
#define WS_BSUM   2097408              // 1024 int
#define WS_ESRC   2101504              // E int

__device__ inline unsigned short f2bf(float f) {
    union { float f; unsigned int i; } v; v.f = f;
    unsigned int r = v.i + 0x7fffu + ((v.i >> 16) & 1u);
    return (unsigned short)(r >> 16);
}
__device__ inline unsigned int pack2(float a, float b) {
    return (unsigned int)f2bf(a) | ((unsigned int)f2bf(b) << 16);
}
__device__ inline uint4 pack8(float4 a, float4 b) {
    return make_uint4(pack2(a.x, a.y), pack2(a.z, a.w),
                      pack2(b.x, b.y), pack2(b.z, b.w));
}
__device__ inline float signed_log(float x) {
    float l = __logf(fabsf(x) + EPS_SL);
    return (x > 0.f) ? l : ((x < 0.f) ? -l : 0.f);
}
// swizzled X store/load: unit index (kb*64+row) ^ (kb&7)
__device__ inline void stx(unsigned short* sX, int kb, int row, uint4 v) {
    *(uint4*)(sX + (((kb * 64 + row) ^ (kb & 7)) * 8)) = v;
}
__device__ inline bf16x8 ldx(const unsigned short* sX, int kb, int row) {
    return *(const bf16x8*)(sX + (((kb * 64 + row) ^ (kb & 7)) * 8));
}

// LDS-only block barrier (no vmcnt drain; r10-proven)
__device__ inline void block_sync_lds() {
    __builtin_amdgcn_sched_barrier(0);
    asm volatile("s_waitcnt lgkmcnt(0)" ::: "memory");
    __builtin_amdgcn_s_barrier();
    __builtin_amdgcn_sched_barrier(0);
}

// ---------------- CSR build ----------------
__global__ void hist_kernel(const int* __restrict__ dst, int* counts, int E) {
    int t = blockIdx.x * blockDim.x + threadIdx.x;
    int e = t * 2;
    if (e + 1 < E) {
        int2 d = *(const int2*)(dst + e);
        atomicAdd(&counts[d.x], 1);
        atomicAdd(&counts[d.y], 1);
    } else if (e < E) {
        atomicAdd(&counts[dst[e]], 1);
    }
}

__global__ void scan_local(int* offs, int* bsum) {
    __shared__ int tmp[256];
    int t = threadIdx.x, i = blockIdx.x * 256 + t;
    int own = offs[i];
    tmp[t] = own;
    __syncthreads();
    for (int off = 1; off < 256; off <<= 1) {
        int v = (t >= off) ? tmp[t - off] : 0;
        __syncthreads();
        tmp[t] += v;
        __syncthreads();
    }
    offs[i] = tmp[t] - own;
    if (t == 255) bsum[blockIdx.x] = tmp[255];
}

// merged: each block computes its own prefix over raw bsum (1024 entries),
// then applies it — removes the separate scan_bsum dispatch.
__global__ void scan_fixup(int* offs, const int* __restrict__ bsum, int* cursor, int E) {
    __shared__ int wsum[4];
    const int b = blockIdx.x;          // 0..1023
    const int t = threadIdx.x;         // 0..255
    int acc = 0;
    #pragma unroll
    for (int j = 0; j < 4; ++j) {
        int idx = j * 256 + t;
        acc += (idx < b) ? bsum[idx] : 0;
    }
    #pragma unroll
    for (int off = 1; off < 64; off <<= 1) acc += __shfl_xor(acc, off);
    if ((t & 63) == 0) wsum[t >> 6] = acc;
    __syncthreads();
    int prefix = wsum[0] + wsum[1] + wsum[2] + wsum[3];
    int i = b * 256 + t;
    int v = offs[i] + prefix;
    offs[i] = v;
    cursor[i] = v;
    if (i == 0) offs[NN] = E;
}

__global__ void fill_kernel(const int* __restrict__ src, const int* __restrict__ dst,
                            int* cursor, int* esrc, int E) {
    int t = blockIdx.x * blockDim.x + threadIdx.x;
    int e = t * 2;
    if (e + 1 < E) {
        int2 s = *(const int2*)(src + e);
        int2 d = *(const int2*)(dst + e);
        int p0 = atomicAdd(&cursor[d.x], 1);
        esrc[p0] = s.x;
        int p1 = atomicAdd(&cursor[d.y], 1);
        esrc[p1] = s.y;
    } else if (e < E) {
        int p = atomicAdd(&cursor[dst[e]], 1);
        esrc[p] = src[e];
    }
}

// ---------------- CSR gather -> upstream bf16 (one row per 512B out slot) ----
__global__ __launch_bounds__(256) void gather_kernel(
    const float4* __restrict__ h4, const int* __restrict__ offs,
    const int* __restrict__ esrc, char* outb)
{
    int stride = gridDim.x * 256;
    for (int idx = blockIdx.x * 256 + threadIdx.x; idx < NN * 16; idx += stride) {
        int n = idx >> 4, c = idx & 15;
        int o0 = offs[n], o1 = offs[n + 1];
        float4 a = make_float4(0.f, 0.f, 0.f, 0.f);
        float4 b = make_float4(0.f, 0.f, 0.f, 0.f);
        for (int e = o0; e < o1; ++e) {
            const float4* hr = h4 + (size_t)esrc[e] * 32 + c * 2;
            float4 p0 = hr[0], p1 = hr[1];
            a.x += p0.x; a.y += p0.y; a.z += p0.z; a.w += p0.w;
            b.x += p1.x; b.y += p1.y; b.z += p1.z; b.w += p1.w;
        }
        *(uint4*)(outb + (size_t)n * 512 + c * 16) = pack8(a, b);
    }
}

// ---------------- fallback atomic scatter ----------------
__global__ void scatter_kernel(const float4* __restrict__ h4,
                               const int* __restrict__ src,
                               const int* __restrict__ dst,
                               float* up, int E) {
    int tid = blockIdx.x * blockDim.x + threadIdx.x;
    int e = tid >> 5;
    if (e >= E) return;
    int c = tid & 31;
    float4 v = h4[(size_t)src[e] * 32 + c];
    float* o = up + (size_t)dst[e] * DD + c * 4;
    atomicAdd(o + 0, v.x);
    atomicAdd(o + 1, v.y);
    atomicAdd(o + 2, v.z);
    atomicAdd(o + 3, v.w);
}

// ---------------- pipelined MFMA node MLP + LayerNorm (r10 champion) --------
// GATHER=1: up = bf16 rows at (char*)out + n*512 (written by gather_kernel)
// GATHER=0: up = fp32 rows in out (written by scatter_kernel)
// Aliasing safe: all slot reads of tile t are consumed at that tile's staging
// stx before B1; the aliased out-stores to those bytes happen after B2.
template <int GATHER>
__global__ __launch_bounds__(THREADS) void node_kernel(
    const float* __restrict__ h, const void* up,
    const float* __restrict__ c1, const float* __restrict__ c2,
    const float* __restrict__ c3, const float* __restrict__ c4,
    const float* __restrict__ qn,
    const float* __restrict__ W1, const float* __restrict__ b1,
    const float* __restrict__ W2, const float* __restrict__ b2,
    const float* __restrict__ gamma, const float* __restrict__ beta,
    float* out)
{
    extern __shared__ char smem[];
    unsigned short* sW1 = (unsigned short*)(smem + OFF_W1);
    unsigned short* sW2 = (unsigned short*)(smem + OFF_W2);
    unsigned short* sX  = (unsigned short*)(smem + OFF_X);
    unsigned short* sH  = (unsigned short*)(smem + OFF_H);
    float2* red = (float2*)(smem + OFF_RED);

    const int tid = threadIdx.x;

    // ---- stage transposed bf16 weights once per block ----
    for (int c = tid; c < 36 * 128; c += THREADS) {
        int kb = c >> 7, n = c & 127;
        unsigned short tmp[8] __attribute__((aligned(16)));
        #pragma unroll
        for (int j = 0; j < 8; ++j) {
            int k = kb * 8 + j;
            tmp[j] = (k < 261) ? f2bf(W1[k * DD + n]) : (unsigned short)0;
        }
        *(uint4*)(sW1 + c * 8) = *(const uint4*)tmp;
    }
    for (int c = tid; c < 16 * 128; c += THREADS) {
        int kb = c >> 7, n = c & 127;
        unsigned short tmp[8] __attribute__((aligned(16)));
        #pragma unroll
        for (int j = 0; j < 8; ++j) tmp[j] = f2bf(W2[(kb * 8 + j) * DD + n]);
        *(uint4*)(sW2 + c * 8) = *(const uint4*)tmp;
    }
    // zero pad rows kb 33..35 once (never overwritten)
    if (tid < 192) {
        int kb = 33 + (tid >> 6), row = tid & 63;
        stx(sX, kb, row, make_uint4(0u, 0u, 0u, 0u));
    }

    const int lane = tid & 63;
    const int w    = tid >> 6;
    const int wm   = w >> 2;
    const int wn   = w & 3;
    const int l15  = lane & 15;
    const int lk   = lane >> 4;
    const int col0 = wn * 32 + l15;
    const int col1 = col0 + 16;

    const float b1v[2] = {b1[col0], b1[col1]};
    const float b2v[2] = {b2[col0], b2[col1]};
    const float gv[2]  = {gamma[col0], gamma[col1]};
    const float bv[2]  = {beta[col0], beta[col1]};

    const bf16x8* W1f = (const bf16x8*)sW1;
    const bf16x8* Hf  = (const bf16x8*)sH;
    const bf16x8* W2f = (const bf16x8*)sW2;

    // chunk coords (loop-invariant): thread owns (k0, r0) and (k0, r0+32)
    const int k0 = tid & 15;
    const int r0 = tid >> 4;          // 0..31

    // prefetch registers
    float4 h0a, h0b, h1a, h1b;
    uint4  u0, u1;                    // GATHER=1
    float4 v0a, v0b, v1a, v1b;        // GATHER=0
    float pc1 = 0.f, pc2 = 0.f, pc3 = 0.f, pc4 = 0.f, pc5 = 0.f;

    // ---- prologue prefetch: tile 0 ----
    {
        int base = blockIdx.x * TPB * TILE_M;
        const float* hp = h + (size_t)(base + r0) * DD + k0 * 8;
        h0a = *(const float4*)hp;       h0b = *(const float4*)(hp + 4);
        h1a = *(const float4*)(hp + 32 * DD); h1b = *(const float4*)(hp + 32 * DD + 4);
        if (GATHER) {
            const char* ub = (const char*)up;
            u0 = *(const uint4*)(ub + (size_t)(base + r0) * 512 + k0 * 16);
            u1 = *(const uint4*)(ub + (size_t)(base + r0 + 32) * 512 + k0 * 16);
        } else {
            const float* uf = (const float*)up + (size_t)(base + r0) * DD + k0 * 8;
            v0a = *(const float4*)uf;       v0b = *(const float4*)(uf + 4);
            v1a = *(const float4*)(uf + 32 * DD); v1b = *(const float4*)(uf + 32 * DD + 4);
        }
        if (tid < 64) {
            int n0 = base + tid;
            pc1 = c1[n0]; pc2 = c2[n0]; pc3 = c3[n0]; pc4 = c4[n0]; pc5 = qn[n0];
        }
    }
    __syncthreads();

    for (int tt = 0; tt < TPB; ++tt) {
        const int base = (blockIdx.x * TPB + tt) * TILE_M;

        // ---- write prefetched regs -> sX ----
        stx(sX, k0, r0,      pack8(h0a, h0b));
        stx(sX, k0, r0 + 32, pack8(h1a, h1b));
        if (GATHER) {
            stx(sX, 16 + k0, r0,      u0);
            stx(sX, 16 + k0, r0 + 32, u1);
        } else {
            stx(sX, 16 + k0, r0,      pack8(v0a, v0b));
            stx(sX, 16 + k0, r0 + 32, pack8(v1a, v1b));
        }
        if (tid < 64) {
            uint4 pv = make_uint4(pack2(signed_log(pc1), signed_log(pc2)),
                                  pack2(signed_log(pc3), signed_log(pc4)),
                                  pack2(signed_log(pc5), 0.f), 0u);
            stx(sX, 32, tid, pv);
        }

        // ---- issue prefetch for next tile (overlaps GEMM + epilogue) ----
        if (tt + 1 < TPB) {
            int bn = base + TILE_M;
            const float* hp = h + (size_t)(bn + r0) * DD + k0 * 8;
            h0a = *(const float4*)hp;       h0b = *(const float4*)(hp + 4);
            h1a = *(const float4*)(hp + 32 * DD); h1b = *(const float4*)(hp + 32 * DD + 4);
            if (GATHER) {
                const char* ub = (const char*)up;
                u0 = *(const uint4*)(ub + (size_t)(bn + r0) * 512 + k0 * 16);
                u1 = *(const uint4*)(ub + (size_t)(bn + r0 + 32) * 512 + k0 * 16);
            } else {
                const float* uf = (const float*)up + (size_t)(bn + r0) * DD + k0 * 8;
                v0a = *(const float4*)uf;       v0b = *(const float4*)(uf + 4);
                v1a = *(const float4*)(uf + 32 * DD); v1b = *(const float4*)(uf + 32 * DD + 4);
            }
            if (tid < 64) {
                int n0 = bn + tid;
                pc1 = c1[n0]; pc2 = c2[n0]; pc3 = c3[n0]; pc4 = c4[n0]; pc5 = qn[n0];
            }
        }
        block_sync_lds();   // B1: sX ready

        // ---- GEMM1: (64x288) @ (288x128) ----
        f32x4 acc[2][2] = {};
        #pragma unroll
        for (int ks = 0; ks < 9; ++ks) {
            int kb = ks * 4 + lk;
            bf16x8 a0  = ldx(sX, kb, wm * 32 + l15);
            bf16x8 a1  = ldx(sX, kb, wm * 32 + 16 + l15);
            bf16x8 bb0 = W1f[kb * 128 + col0];
            bf16x8 bb1 = W1f[kb * 128 + col1];
            acc[0][0] = __builtin_amdgcn_mfma_f32_16x16x32_bf16(a0, bb0, acc[0][0], 0, 0, 0);
            acc[0][1] = __builtin_amdgcn_mfma_f32_16x16x32_bf16(a0, bb1, acc[0][1], 0, 0, 0);
            acc[1][0] = __builtin_amdgcn_mfma_f32_16x16x32_bf16(a1, bb0, acc[1][0], 0, 0, 0);
            acc[1][1] = __builtin_amdgcn_mfma_f32_16x16x32_bf16(a1, bb1, acc[1][1], 0, 0, 0);
        }
        // silu -> hid tile
        #pragma unroll
        for (int fm = 0; fm < 2; ++fm) {
            int row = wm * 32 + fm * 16 + lk * 4;
            #pragma unroll
            for (int fn = 0; fn < 2; ++fn) {
                int col = wn * 32 + fn * 16 + l15;
                int kbh = col >> 3, ko = col & 7;
                #pragma unroll
                for (int r = 0; r < 4; ++r) {
                    float v = acc[fm][fn][r] + b1v[fn];
                    float sg = 1.f / (1.f + __expf(-v));
                    sH[(kbh * 64 + row + r) * 8 + ko] = f2bf(v * sg);
                }
            }
        }
        block_sync_lds();   // B2: sH ready

        // ---- GEMM2: (64x128) @ (128x128) ----
        f32x4 acc2[2][2] = {};
        #pragma unroll
        for (int ks = 0; ks < 4; ++ks) {
            int kb = ks * 4 + lk;
            bf16x8 a0  = Hf[kb * 64 + wm * 32 + l15];
            bf16x8 a1  = Hf[kb * 64 + wm * 32 + 16 + l15];
            bf16x8 bb0 = W2f[kb * 128 + col0];
            bf16x8 bb1 = W2f[kb * 128 + col1];
            acc2[0][0] = __builtin_amdgcn_mfma_f32_16x16x32_bf16(a0, bb0, acc2[0][0], 0, 0, 0);
            acc2[0][1] = __builtin_amdgcn_mfma_f32_16x16x32_bf16(a0, bb1, acc2[0][1], 0, 0, 0);
            acc2[1][0] = __builtin_amdgcn_mfma_f32_16x16x32_bf16(a1, bb0, acc2[1][0], 0, 0, 0);
            acc2[1][1] = __builtin_amdgcn_mfma_f32_16x16x32_bf16(a1, bb1, acc2[1][1], 0, 0, 0);
        }

        // ---- residual + LN partials ----
        float rs1[2][4], rs2[2][4];
        #pragma unroll
        for (int fm = 0; fm < 2; ++fm) {
            #pragma unroll
            for (int r = 0; r < 4; ++r) {
                size_t rowg = (size_t)(base + wm * 32 + fm * 16 + lk * 4 + r) * DD;
                float z0 = acc2[fm][0][r] + b2v[0] + h[rowg + col0];
                float z1 = acc2[fm][1][r] + b2v[1] + h[rowg + col1];
                acc2[fm][0][r] = z0; acc2[fm][1][r] = z1;
                float s = z0 + z1, q = z0 * z0 + z1 * z1;
                #pragma unroll
                for (int off = 1; off < 16; off <<= 1) {
                    s += __shfl_xor(s, off);
                    q += __shfl_xor(q, off);
                }
                rs1[fm][r] = s; rs2[fm][r] = q;
            }
        }
        if (l15 == 0) {
            #pragma unroll
            for (int fm = 0; fm < 2; ++fm)
                #pragma unroll
                for (int r = 0; r < 4; ++r)
                    red[wn * 64 + wm * 32 + fm * 16 + lk * 4 + r] =
                        make_float2(rs1[fm][r], rs2[fm][r]);
        }
        block_sync_lds();   // B3: red ready

        #pragma unroll
        for (int fm = 0; fm < 2; ++fm) {
            #pragma unroll
            for (int r = 0; r < 4; ++r) {
                int rloc = wm * 32 + fm * 16 + lk * 4 + r;
                float2 t0 = red[rloc], t1 = red[64 + rloc],
                       t2 = red[128 + rloc], t3 = red[192 + rloc];
                float S = t0.x + t1.x + t2.x + t3.x;
                float Q = t0.y + t1.y + t2.y + t3.y;
                float mean = S * (1.f / 128.f);
                float var  = Q * (1.f / 128.f) - mean * mean;
                float rstd = rsqrtf(var + EPS_LN);
                size_t rowg = (size_t)(base + rloc) * DD;
                out[rowg + col0] = (acc2[fm][0][r] - mean) * rstd * gv[0] + bv[0];
                out[rowg + col1] = (acc2[fm][1][r] - mean) * rstd * gv[1] + bv[1];
            }
        }
        // loop back: sX rewrite is 2+ barriers after last sX read -> safe
    }
}

extern "C" void kernel_launch(void* const* d_in, const int* in_sizes, int n_in,
                              void* d_out, int out_size, void* d_ws, size_t ws_size,
                              hipStream_t stream) {
    const float* h     = (const float*)d_in[0];
    const float* c1    = (const float*)d_in[1];
    const float* c2    = (const float*)d_in[2];
    const float* c3    = (const float*)d_in[3];
    const float* c4    = (const float*)d_in[4];
    const float* qn    = (const float*)d_in[5];
    const int*   src   = (const int*)d_in[6];
    const int*   dst   = (const int*)d_in[7];
    const float* W1    = (const float*)d_in[8];
    const float* b1    = (const float*)d_in[9];
    const float* W2    = (const float*)d_in[10];
    const float* b2    = (const float*)d_in[11];
    const float* gamma = (const float*)d_in[12];
    const float* beta  = (const float*)d_in[13];
    float* out = (float*)d_out;
    int E = in_sizes[6];
    size_t ws_needed = (size_t)WS_ESRC + (size_t)E * 4;

    if (ws_size >= ws_needed) {
        char* ws = (char*)d_ws;
        int* offs   = (int*)(ws + WS_OFFS);
        int* cursor = (int*)(ws + WS_CURSOR);
        int* bsum   = (int*)(ws + WS_BSUM);
        int* esrc   = (int*)(ws + WS_ESRC);

        hipMemsetAsync(offs, 0, (size_t)NN * sizeof(int), stream);
        int eb2 = (E / 2 + 255) / 256;
        hist_kernel<<<eb2, 256, 0, stream>>>(dst, offs, E);
        scan_local<<<NN / 256, 256, 0, stream>>>(offs, bsum);
        scan_fixup<<<NN / 256, 256, 0, stream>>>(offs, bsum, cursor, E);
        fill_kernel<<<eb2, 256, 0, stream>>>(src, dst, cursor, esrc, E);

        gather_kernel<<<2048, 256, 0, stream>>>((const float4*)h, offs, esrc, (char*)d_out);

        hipFuncSetAttribute(reinterpret_cast<const void*>(&node_kernel<1>),
                            hipFuncAttributeMaxDynamicSharedMemorySize, SMEM_TOT);
        node_kernel<1><<<NBLOCKS, THREADS, SMEM_TOT, stream>>>(
            h, d_out, c1, c2, c3, c4, qn,
            W1, b1, W2, b2, gamma, beta, out);
    } else {
        // fallback: atomic scatter into d_out (fp32 upstream)
        hipMemsetAsync(d_out, 0, (size_t)NN * DD * sizeof(float), stream);
        int sthreads = E * 32;
        int sblocks = (sthreads + 255) / 256;
        scatter_kernel<<<sblocks, 256, 0, stream>>>((const float4*)h, src, dst, out, E);
        hipFuncSetAttribute(reinterpret_cast<const void*>(&node_kernel<0>),
                            hipFuncAttributeMaxDynamicSharedMemorySize, SMEM_TOT);
        node_kernel<0><<<NBLOCKS, THREADS, SMEM_TOT, stream>>>(
            h, d_out, c1, c2, c3, c4, qn,
            W1, b1, W2, b2, gamma, beta, out);
    }
}